// Round 6
// baseline (160.314 us; speedup 1.0000x reference)
//
#include <hip/hip_runtime.h>

#define BATCH 32
#define H 512
#define W 512
#define WIN 9
#define SEG 16                      // output rows per block
#define TPB 128                     // threads; x4 cols each = 512 cols = full row
// final scalar = sum over pixels of ((1-cc1)+(1-cc2)) * 0.5 / (B*H*W)
#define SCALE (0.5f / 8388608.0f)

typedef float f32x4 __attribute__((ext_vector_type(4)));

__global__ __launch_bounds__(TPB) void ncc_loss_kernel(
    const float* __restrict__ g1, const float* __restrict__ g2,
    const float* __restrict__ gf, float* __restrict__ out)
{
    const int t  = threadIdx.x;                      // owns cols 4t..4t+3
    const int y0 = blockIdx.y * SEG;
    const int b  = blockIdx.z;
    const size_t base = (size_t)b * (H * W);

    // three 16B-aligned x4 loads cover window cols [4t-4, 4t+7].
    // lane 0's first load would be voffset -16 (wrap hazard) -> clamp + zero.
    const int  voL   = (t == 0) ? 0 : (16 * t - 16);
    const bool lane0 = (t == 0);

    // vertical running sums, 8 quantities x 4 columns (registers)
    float v1[4], v2[4], vf[4], v11[4], v22[4], vff[4], v1f[4], v2f[4];
#pragma unroll
    for (int c = 0; c < 4; ++c) {
        v1[c]=0.f; v2[c]=0.f; vf[c]=0.f; v11[c]=0.f;
        v22[c]=0.f; vff[c]=0.f; v1f[c]=0.f; v2f[c]=0.f;
    }
    float lsum = 0.f;
    const float inv_n = 1.0f / 81.0f;

    // load one raw row (12 floats x 3 images) with HW zero-padding:
    // OOB rows via num_records=0; OOB cols via SRD bounds check (and lane-0 mask)
    auto load_row = [&](int yr, float* wa, float* wc, float* wf) {
        const int rec = ((unsigned)yr < (unsigned)H) ? (W * 4) : 0;
        const int yc  = yr < 0 ? 0 : (yr >= H ? H - 1 : yr);
        const size_t roff = base + (size_t)yc * W;
        __amdgpu_buffer_rsrc_t ra = __builtin_amdgcn_make_buffer_rsrc(
            (void*)(g1 + roff), (short)0, rec, 0x00020000);
        __amdgpu_buffer_rsrc_t rc = __builtin_amdgcn_make_buffer_rsrc(
            (void*)(g2 + roff), (short)0, rec, 0x00020000);
        __amdgpu_buffer_rsrc_t rf = __builtin_amdgcn_make_buffer_rsrc(
            (void*)(gf + roff), (short)0, rec, 0x00020000);
        f32x4 a0 = __builtin_bit_cast(f32x4, __builtin_amdgcn_raw_buffer_load_b128(ra, voL, 0, 0));
        f32x4 c0 = __builtin_bit_cast(f32x4, __builtin_amdgcn_raw_buffer_load_b128(rc, voL, 0, 0));
        f32x4 f0 = __builtin_bit_cast(f32x4, __builtin_amdgcn_raw_buffer_load_b128(rf, voL, 0, 0));
        f32x4 a1 = __builtin_bit_cast(f32x4, __builtin_amdgcn_raw_buffer_load_b128(ra, 16*t,    0, 0));
        f32x4 c1 = __builtin_bit_cast(f32x4, __builtin_amdgcn_raw_buffer_load_b128(rc, 16*t,    0, 0));
        f32x4 f1 = __builtin_bit_cast(f32x4, __builtin_amdgcn_raw_buffer_load_b128(rf, 16*t,    0, 0));
        f32x4 a2 = __builtin_bit_cast(f32x4, __builtin_amdgcn_raw_buffer_load_b128(ra, 16*t+16, 0, 0));
        f32x4 c2 = __builtin_bit_cast(f32x4, __builtin_amdgcn_raw_buffer_load_b128(rc, 16*t+16, 0, 0));
        f32x4 f2 = __builtin_bit_cast(f32x4, __builtin_amdgcn_raw_buffer_load_b128(rf, 16*t+16, 0, 0));
        if (lane0) { a0 = 0.f; c0 = 0.f; f0 = 0.f; }   // true left-edge zeros
#pragma unroll
        for (int i = 0; i < 4; ++i) {
            wa[i] = a0[i]; wa[4+i] = a1[i]; wa[8+i] = a2[i];
            wc[i] = c0[i]; wc[4+i] = c1[i]; wc[8+i] = c2[i];
            wf[i] = f0[i]; wf[4+i] = f1[i]; wf[8+i] = f2[i];
        }
    };

    // 4 sliding 9-window sums from 12 values (raw)
    auto hwin = [&](const float* w, float* h) {
        float s = w[0]+w[1]+w[2]+w[3]+w[4]+w[5]+w[6]+w[7]+w[8];
        h[0]=s; s += w[9]-w[0]; h[1]=s; s += w[10]-w[1]; h[2]=s; s += w[11]-w[2]; h[3]=s;
    };
    // same for elementwise products u*w
    auto hwinp = [&](const float* u, const float* w, float* h) {
        const float p0=u[0]*w[0], p1=u[1]*w[1], p2=u[2]*w[2];
        float s = p0+p1+p2;
#pragma unroll
        for (int i = 3; i <= 8; ++i) s = fmaf(u[i], w[i], s);
        h[0]=s; s = fmaf(u[9],w[9],s)-p0; h[1]=s;
        s = fmaf(u[10],w[10],s)-p1; h[2]=s;
        s = fmaf(u[11],w[11],s)-p2; h[3]=s;
    };

    // add (enter) or subtract (leave) one row's window sums into v
    auto consume = [&](const float* wa, const float* wc, const float* wf, bool sub) {
        float ha[4],hc[4],hf[4],haa[4],hcc[4],hff[4],haf[4],hcf[4];
        hwin(wa,ha); hwin(wc,hc); hwin(wf,hf);
        hwinp(wa,wa,haa); hwinp(wc,wc,hcc); hwinp(wf,wf,hff);
        hwinp(wa,wf,haf); hwinp(wc,wf,hcf);
#pragma unroll
        for (int c = 0; c < 4; ++c) {
            if (!sub) {
                v1[c]+=ha[c]; v2[c]+=hc[c]; vf[c]+=hf[c]; v11[c]+=haa[c];
                v22[c]+=hcc[c]; vff[c]+=hff[c]; v1f[c]+=haf[c]; v2f[c]+=hcf[c];
            } else {
                v1[c]-=ha[c]; v2[c]-=hc[c]; vf[c]-=hf[c]; v11[c]-=haa[c];
                v22[c]-=hcc[c]; vff[c]-=hff[c]; v1f[c]-=haf[c]; v2f[c]-=hcf[c];
            }
        }
    };

    auto emit = [&]() {
#pragma unroll
        for (int c = 0; c < 4; ++c) {
            const float u1 = v1[c]*inv_n, u2 = v2[c]*inv_n, uf = vf[c]*inv_n;
            const float cross1 = fmaf(-v1[c], uf, v1f[c]);
            const float var1   = fmaf(-v1[c], u1, v11[c]);
            const float varf   = fmaf(-vf[c], uf, vff[c]);
            const float cross2 = fmaf(-v2[c], uf, v2f[c]);
            const float var2   = fmaf(-v2[c], u2, v22[c]);
            const float d1 = fmaf(var1, varf, 1e-5f);
            const float d2 = fmaf(var2, varf, 1e-5f);
            const float inv = __builtin_amdgcn_rcpf(d1 * d2);
            float num = cross1 * cross1 * d2;
            num = fmaf(cross2 * cross2, d1, num);
            lsum += fmaf(-num, inv, 2.0f);
        }
    };

    // double-buffered prefetch registers (parities are source-literal)
    float EA[2][12], EC[2][12], EF[2][12];   // entering rows
    float LA[2][12], LC[2][12], LF[2][12];   // leaving rows

    // ---- prologue: accumulate rows y0-4 .. y0+3 (software-pipelined) ----
    load_row(y0 - 4, EA[0], EC[0], EF[0]);
#pragma unroll 1
    for (int s = 0; s < 8; s += 2) {
        load_row(y0 - 3 + s, EA[1], EC[1], EF[1]);              // row s+1
        consume(EA[0], EC[0], EF[0], false);                    // row s
        if (s + 2 < 8) load_row(y0 - 2 + s, EA[0], EC[0], EF[0]);   // row s+2
        else           load_row(y0 + 4,     EA[0], EC[0], EF[0]);   // enter(j=0)
        consume(EA[1], EC[1], EF[1], false);                    // row s+1
    }
    load_row(y0 - 4, LA[0], LC[0], LF[0]);                      // leave(j=0)

    // ---- main: per output row j: enter y0+4+j, emit, leave y0-4+j ----
#pragma unroll 1
    for (int jo = 0; jo < SEG; jo += 2) {
        // j = jo  (parity 0), prefetch j+1 into parity 1
        load_row(y0 + 5 + jo, EA[1], EC[1], EF[1]);
        load_row(y0 - 3 + jo, LA[1], LC[1], LF[1]);
        consume(EA[0], EC[0], EF[0], false);
        emit();
        consume(LA[0], LC[0], LF[0], true);
        // j = jo+1 (parity 1), prefetch j+2 into parity 0
        if (jo + 2 < SEG) {
            load_row(y0 + 6 + jo, EA[0], EC[0], EF[0]);
            load_row(y0 - 2 + jo, LA[0], LC[0], LF[0]);
        }
        consume(EA[1], EC[1], EF[1], false);
        emit();
        consume(LA[1], LC[1], LF[1], true);
    }

    // block reduction: wave shuffle -> LDS -> one atomic per block
#pragma unroll
    for (int o = 32; o > 0; o >>= 1)
        lsum += __shfl_down(lsum, o);
    __shared__ float wsum[2];
    if ((t & 63) == 0) wsum[t >> 6] = lsum;
    __syncthreads();
    if (t == 0) atomicAdd(out, (wsum[0] + wsum[1]) * SCALE);
}

extern "C" void kernel_launch(void* const* d_in, const int* in_sizes, int n_in,
                              void* d_out, int out_size, void* d_ws, size_t ws_size,
                              hipStream_t stream) {
    const float* img1 = (const float*)d_in[0];
    const float* img2 = (const float*)d_in[1];
    const float* fimg = (const float*)d_in[2];
    float* out = (float*)d_out;

    hipMemsetAsync(out, 0, sizeof(float), stream);  // d_out re-poisoned each call

    dim3 grid(1, H / SEG, BATCH);   // (1, 32, 32) = 1024 blocks x 128 threads
    ncc_loss_kernel<<<grid, dim3(TPB), 0, stream>>>(img1, img2, fimg, out);
}